// Round 5
// baseline (408.738 us; speedup 1.0000x reference)
//
#include <hip/hip_runtime.h>

// QuerySHLayerDeprecated: per-edge SH(lmax=2) + smooth radial basis embed.
//   d_in[0] = pos        f32[100000*3]
//   d_in[1] = query_pos  f32[10000*3]
//   d_in[2] = edge_src   int32[4000000]  (rows of query_pos)
//   d_in[3] = edge_dst   int32[4000000]  (rows of pos)
// Output: edge_sh[4M*9] then edge_embed[4M*10], f32 flat concat.
//
// R8: R5 (stores) and R6 (occupancy) null, R7 (fewer gathers, 4 waves)
// regressed -> model: gather path is L1-MSHR-throughput bound
// (rate = MSHRs/L2-latency ~ 20/300cy ~ 0.068 lines/cy, matches calib).
// Fix: nt-load the table gathers so they don't allocate/track in L1
// (tables are L2-resident, L1 hit rate ~0 anyway) -> concurrency moves
// to the per-wave vmcnt queue. Base = R6 (best cfg, 8 blocks/CU,
// 32 waves/CU); ONLY the two gathers changed to nontemporal.

#define SQRT3F 1.7320508075688772f
// SMOOTH_C * sqrt(10) = 1.14136 * e^2 * sqrt(10)
#define EMB_K 26.6692997f
#define TPB 256
#define EPB 256                  // edges per block (1 per thread)
#define NSH4 (EPB * 9 / 4)       // 576 float4s of SH per block
#define NEM4 (EPB * 10 / 4)      // 640 float4s of embed per block

typedef float floatx4 __attribute__((ext_vector_type(4)));

__global__ __launch_bounds__(256) void pad_kernel(
    const float* __restrict__ pos, const float* __restrict__ qpos,
    float4* __restrict__ pos4, float4* __restrict__ qpos4,
    int npos, int nq)
{
    int i = blockIdx.x * blockDim.x + threadIdx.x;
    if (i < npos)
        pos4[i] = make_float4(pos[3 * i + 0], pos[3 * i + 1], pos[3 * i + 2], 0.f);
    if (i < nq)
        qpos4[i] = make_float4(qpos[3 * i + 0], qpos[3 * i + 1], qpos[3 * i + 2], 0.f);
}

// Compute one edge: 9 SH values into sh[0..8] (word-stride-9 LDS row,
// odd stride -> 2-way bank alias only, free), 10 embed values into em2
// (5 float2 zero writes + <=2 scalar overwrites in the active window).
__device__ __forceinline__ void compute_edge(
    float ax, float ay, float az, float bx, float by, float bz,
    float* __restrict__ sh, float2* __restrict__ em2)
{
    float vx = ax - bx, vy = ay - by, vz = az - bz;
    float r2 = vx * vx + vy * vy + vz * vz;
    float r = sqrtf(r2);
    float inv = (r > 0.f) ? (1.f / r) : 1.f;
    float x = vx * inv, y = vy * inv, z = vz * inv;

    sh[0] = 1.f;
    sh[1] = x;
    sh[2] = y;
    sh[3] = z;
    sh[4] = SQRT3F * x * z;
    sh[5] = SQRT3F * x * y;
    sh[6] = y * y - 0.5f * (x * x + z * z);
    sh[7] = SQRT3F * y * z;
    sh[8] = 0.5f * SQRT3F * (z * z - x * x);

    // zero-fill embed row (vector LDS writes), then set the window.
#pragma unroll
    for (int j = 0; j < 5; ++j) em2[j] = make_float2(0.f, 0.f);

    // embed: t = 11*r; basis j nonzero only for t in (j, j+2); windows
    // overlap by 1 => at most two nonzero, j in {floor(t)-1, floor(t)}.
    float t = r * 11.f;
    int k = (int)t;  // t >= 0, trunc == floor
    float* e = (float*)em2;
#pragma unroll
    for (int m = 0; m < 2; ++m) {
        int j = k - 1 + m;
        float a = t - (float)j;
        float b = (float)(j + 2) - t;
        if (j >= 0 && j < 10 && a > 0.f && b > 0.f)
            e[j] = EMB_K * __expf(-(__frcp_rn(a) + __frcp_rn(b)));
    }
}

template <bool PAD>
__global__ __launch_bounds__(256, 8) void qsh_kernel(
    const float* __restrict__ pos,
    const float* __restrict__ qpos,
    const floatx4* __restrict__ pos4,
    const floatx4* __restrict__ qpos4,
    const int* __restrict__ esrc,
    const int* __restrict__ edst,
    float* __restrict__ out_sh,
    float* __restrict__ out_emb,
    int n)
{
    // LDS layout == output layout: contiguous [256*9] and [256*10].
    // Total 19.5 KB -> 8 blocks/CU -> 32 waves/CU.
    __shared__ __align__(16) float sh_lds[EPB * 9];
    __shared__ __align__(16) float emb_lds[EPB * 10];

    const int tid = threadIdx.x;
    const int base = blockIdx.x * EPB;
    const int count = min(EPB, n - base);

    if (tid < count) {
        int e = base + tid;
        // nontemporal: 32MB index streams must not thrash L1/L2
        int s = __builtin_nontemporal_load(esrc + e);
        int d = __builtin_nontemporal_load(edst + e);
        float ax, ay, az, bx, by, bz;
        if (PAD) {
            // nt gathers: tables are L2-resident, L1 hit ~0 -> don't
            // allocate in L1 / don't consume L1 fill-tracking slots.
            floatx4 q = __builtin_nontemporal_load(qpos4 + s);
            floatx4 p = __builtin_nontemporal_load(pos4 + d);
            ax = q.x; ay = q.y; az = q.z;
            bx = p.x; by = p.y; bz = p.z;
        } else {
            ax = qpos[3 * s + 0]; ay = qpos[3 * s + 1]; az = qpos[3 * s + 2];
            bx = pos[3 * d + 0];  by = pos[3 * d + 1];  bz = pos[3 * d + 2];
        }
        compute_edge(ax, ay, az, bx, by, bz,
                     sh_lds + tid * 9, (float2*)(emb_lds + tid * 10));
    }
    __syncthreads();

    // Pure memcpy writeback: ds_read_b128 + nontemporal global_store_dwordx4.
    // Block base offsets: base*9 and base*10 words are both /4 -> 16B aligned.
    floatx4* osh4 = (floatx4*)(out_sh + (size_t)base * 9);
    floatx4* oem4 = (floatx4*)(out_emb + (size_t)base * 10);
    const floatx4* shv = (const floatx4*)sh_lds;
    const floatx4* emv = (const floatx4*)emb_lds;

    if (count == EPB) {
#pragma unroll
        for (int k = 0; k < 3; ++k) {          // 576 = 2.25*256
            int i4 = k * TPB + tid;
            if (i4 < NSH4)
                __builtin_nontemporal_store(shv[i4], osh4 + i4);
        }
#pragma unroll
        for (int k = 0; k < 3; ++k) {          // 640 = 2.5*256
            int i4 = k * TPB + tid;
            if (i4 < NEM4)
                __builtin_nontemporal_store(emv[i4], oem4 + i4);
        }
    } else {
        float* osh = out_sh + (size_t)base * 9;
        float* oem = out_emb + (size_t)base * 10;
        int nsh = count * 9;
        for (int idx = tid; idx < nsh; idx += TPB)
            __builtin_nontemporal_store(sh_lds[idx], osh + idx);
        int nem = count * 10;
        for (int idx = tid; idx < nem; idx += TPB)
            __builtin_nontemporal_store(emb_lds[idx], oem + idx);
    }
}

extern "C" void kernel_launch(void* const* d_in, const int* in_sizes, int n_in,
                              void* d_out, int out_size, void* d_ws, size_t ws_size,
                              hipStream_t stream) {
    const float* pos  = (const float*)d_in[0];
    const float* qpos = (const float*)d_in[1];
    const int* esrc = (const int*)d_in[2];
    const int* edst = (const int*)d_in[3];
    int npos = in_sizes[0] / 3;   // 100000
    int nq   = in_sizes[1] / 3;   // 10000
    int n    = in_sizes[2];       // 4,000,000 edges

    float* out_sh  = (float*)d_out;
    float* out_emb = out_sh + (size_t)n * 9;

    int grid = (n + EPB - 1) / EPB;

    size_t need = ((size_t)npos + (size_t)nq) * sizeof(float4);
    if (ws_size >= need) {
        float4* pos4  = (float4*)d_ws;
        float4* qpos4 = pos4 + npos;
        int pgrid = (max(npos, nq) + TPB - 1) / TPB;
        pad_kernel<<<pgrid, TPB, 0, stream>>>(pos, qpos, pos4, qpos4, npos, nq);
        qsh_kernel<true><<<grid, TPB, 0, stream>>>(
            pos, qpos, (const floatx4*)pos4, (const floatx4*)qpos4,
            esrc, edst, out_sh, out_emb, n);
    } else {
        qsh_kernel<false><<<grid, TPB, 0, stream>>>(
            pos, qpos, nullptr, nullptr, esrc, edst, out_sh, out_emb, n);
    }
}

// Round 7
// 350.706 us; speedup vs baseline: 1.1655x; 1.1655x over previous
//
#include <hip/hip_runtime.h>

// QuerySHLayerDeprecated: per-edge SH(lmax=2) + smooth radial basis embed.
//   d_in[0] = pos        f32[100000*3]
//   d_in[1] = query_pos  f32[10000*3]
//   d_in[2] = edge_src   int32[4000000]  (rows of query_pos)
//   d_in[3] = edge_dst   int32[4000000]  (rows of pos)
// Output: edge_sh[4M*9] then edge_embed[4M*10], f32 flat concat.
//
// R10 = R9 resubmit (container infra flake, no data). Theory unchanged:
// L1-miss-throughput bound (~15 cy/miss/CU): R5 store-vectorize null,
// R6 32-wave null, R7 qpos-LDS@4waves regress, R8 nt-gather regress.
// Lever = fewer misses at >=16 waves: whole 120KB qpos in LDS (kills
// ~0.8 miss/edge), ONE 1024-thread block per CU (16 waves), persistent +
// grid-stride. Staging LDS fits 512 rows next to qpos, so each 1024-edge
// chunk runs as two 512-edge compute/writeback phases; barriers are raw
// s_barrier + lgkmcnt-only (pos4 prefetch gathers stay in flight across
// them). Idx prefetched 2 chunks ahead, gather 1 chunk ahead.
// Barrier-uniformity audit: every barrier is executed by all 1024 threads
// (guards cover compute/stores only); count/have1 are block-uniform.

#define SQRT3F 1.7320508075688772f
// SMOOTH_C * sqrt(10) = 1.14136 * e^2 * sqrt(10)
#define EMB_K 26.6692997f
#define TPB 1024
#define EPB 1024                 // edges per chunk (1 per thread)
#define HALF 512                 // staging rows per phase
#define NQF 30000                // qpos floats (10000*3) = 120000 B
#define QSH_GRID 256             // persistent: 1 block per CU

typedef float floatx4 __attribute__((ext_vector_type(4)));

__global__ __launch_bounds__(256) void pad_kernel(
    const float* __restrict__ pos, float4* __restrict__ pos4, int npos)
{
    int i = blockIdx.x * blockDim.x + threadIdx.x;
    if (i < npos)
        pos4[i] = make_float4(pos[3 * i + 0], pos[3 * i + 1], pos[3 * i + 2], 0.f);
}

// 9 SH values -> sh row (word stride 9: odd -> free 2-way bank alias),
// 10 embed values -> em2 (5 float2 zeros + <=2 scalar window overwrites;
// LDS pointer so the runtime index j never touches a register array).
__device__ __forceinline__ void compute_edge(
    float ax, float ay, float az, float bx, float by, float bz,
    float* __restrict__ sh, float2* __restrict__ em2)
{
    float vx = ax - bx, vy = ay - by, vz = az - bz;
    float r2 = vx * vx + vy * vy + vz * vz;
    float r = sqrtf(r2);
    float inv = (r > 0.f) ? (1.f / r) : 1.f;
    float x = vx * inv, y = vy * inv, z = vz * inv;

    sh[0] = 1.f;
    sh[1] = x;
    sh[2] = y;
    sh[3] = z;
    sh[4] = SQRT3F * x * z;
    sh[5] = SQRT3F * x * y;
    sh[6] = y * y - 0.5f * (x * x + z * z);
    sh[7] = SQRT3F * y * z;
    sh[8] = 0.5f * SQRT3F * (z * z - x * x);

#pragma unroll
    for (int j = 0; j < 5; ++j) em2[j] = make_float2(0.f, 0.f);

    // embed: t = 11*r; basis j nonzero only for t in (j, j+2); at most two
    // nonzero, j in {floor(t)-1, floor(t)}.
    float t = r * 11.f;
    int k = (int)t;
    float* e = (float*)em2;
#pragma unroll
    for (int m = 0; m < 2; ++m) {
        int j = k - 1 + m;
        float a = t - (float)j;
        float b = (float)(j + 2) - t;
        if (j >= 0 && j < 10 && a > 0.f && b > 0.f)
            e[j] = EMB_K * __expf(-(__frcp_rn(a) + __frcp_rn(b)));
    }
}

__device__ __forceinline__ void writeback_half(
    const float* __restrict__ sh_lds, const float* __restrict__ emb_lds,
    float* __restrict__ out_sh, float* __restrict__ out_emb,
    size_t obase, int h, int tid)
{
    if (h == HALF) {
        // 512*9 = 1152 float4s, 512*10 = 1280 float4s; 1024 threads.
        floatx4* osh4 = (floatx4*)(out_sh + obase * 9);
        floatx4* oem4 = (floatx4*)(out_emb + obase * 10);
        const floatx4* shv = (const floatx4*)sh_lds;
        const floatx4* emv = (const floatx4*)emb_lds;
        __builtin_nontemporal_store(shv[tid], osh4 + tid);
        if (tid + TPB < 1152)
            __builtin_nontemporal_store(shv[tid + TPB], osh4 + tid + TPB);
        __builtin_nontemporal_store(emv[tid], oem4 + tid);
        if (tid + TPB < 1280)
            __builtin_nontemporal_store(emv[tid + TPB], oem4 + tid + TPB);
    } else {
        float* osh = out_sh + obase * 9;
        float* oem = out_emb + obase * 10;
        int nsh = h * 9;
        for (int idx = tid; idx < nsh; idx += TPB)
            __builtin_nontemporal_store(sh_lds[idx], osh + idx);
        int nem = h * 10;
        for (int idx = tid; idx < nem; idx += TPB)
            __builtin_nontemporal_store(emb_lds[idx], oem + idx);
    }
}

#define LDS_BARRIER() do {                                   \
    asm volatile("s_waitcnt lgkmcnt(0)" ::: "memory");       \
    __builtin_amdgcn_s_barrier();                            \
    __builtin_amdgcn_sched_barrier(0);                       \
} while (0)

template <bool PAD>
__global__ __launch_bounds__(1024, 1) void qsh_kernel(
    const float* __restrict__ pos,
    const float* __restrict__ qpos,
    const floatx4* __restrict__ pos4,
    const int* __restrict__ esrc,
    const int* __restrict__ edst,
    float* __restrict__ out_sh,
    float* __restrict__ out_emb,
    int n)
{
    __shared__ float qp[NQF];                         // 120000 B
    __shared__ __align__(16) float sh_lds[HALF * 9];  // 18432 B
    __shared__ __align__(16) float emb_lds[HALF * 10];// 20480 B => 158912 B

    const int tid = threadIdx.x;

    // Stage the whole qpos table once per persistent block (coalesced x4;
    // 30000 floats = 7500 float4s exactly).
    {
        const floatx4* src = (const floatx4*)qpos;
        floatx4* dst = (floatx4*)qp;
        for (int i = tid; i < NQF / 4; i += TPB) dst[i] = src[i];
    }
    __syncthreads();

    const int nchunk = (n + EPB - 1) / EPB;
    const int G = gridDim.x;
    int c = blockIdx.x;
    if (c >= nchunk) return;

    // Prologue: idx + pos-gather for chunk c; idx for chunk c+G.
    int e0 = c * EPB + tid; if (e0 >= n) e0 = n - 1;
    int s0 = __builtin_nontemporal_load(esrc + e0);
    int d0 = __builtin_nontemporal_load(edst + e0);
    float bx0, by0, bz0;
    if (PAD) { floatx4 t = pos4[d0]; bx0 = t.x; by0 = t.y; bz0 = t.z; }
    else { bx0 = pos[3*d0]; by0 = pos[3*d0+1]; bz0 = pos[3*d0+2]; }

    int c1 = c + G;
    int s1 = s0, d1 = d0;
    if (c1 < nchunk) {
        int e1 = c1 * EPB + tid; if (e1 >= n) e1 = n - 1;
        s1 = __builtin_nontemporal_load(esrc + e1);
        d1 = __builtin_nontemporal_load(edst + e1);
    }

    while (true) {
        const int base = c * EPB;
        const int count = min(EPB, n - base);

        // qpos for this thread's edge from LDS (all threads; phase-2
        // threads keep theirs in regs across the barriers).
        float ax = qp[3 * s0], ay = qp[3 * s0 + 1], az = qp[3 * s0 + 2];

        // ---- phase 1 compute: edges [base, base+HALF) -> rows [0,HALF)
        if (tid < HALF && tid < count)
            compute_edge(ax, ay, az, bx0, by0, bz0,
                         sh_lds + tid * 9, (float2*)(emb_lds + tid * 10));

        // ---- prefetch next chunk: pos gather (c1) + idx (c2). Issued by
        // all 16 waves (phase-2 waves reach here immediately) and kept in
        // flight across the lgkmcnt-only barriers below.
        const bool have1 = (c1 < nchunk);
        float bx1 = bx0, by1 = by0, bz1 = bz0;
        if (have1) {
            if (PAD) { floatx4 t = pos4[d1]; bx1 = t.x; by1 = t.y; bz1 = t.z; }
            else { bx1 = pos[3*d1]; by1 = pos[3*d1+1]; bz1 = pos[3*d1+2]; }
        }
        int c2 = c1 + G, s2 = s1, d2 = d1;
        if (have1 && c2 < nchunk) {
            int e2 = c2 * EPB + tid; if (e2 >= n) e2 = n - 1;
            s2 = __builtin_nontemporal_load(esrc + e2);
            d2 = __builtin_nontemporal_load(edst + e2);
        }

        LDS_BARRIER();                       // phase-1 rows visible

        int h1 = min(HALF, count);
        writeback_half(sh_lds, emb_lds, out_sh, out_emb, (size_t)base, h1, tid);

        LDS_BARRIER();                       // staging reads done

        // ---- phase 2 compute: edges [base+HALF, base+count) -> rows [0,..)
        if (tid >= HALF && tid < count)
            compute_edge(ax, ay, az, bx0, by0, bz0,
                         sh_lds + (tid - HALF) * 9,
                         (float2*)(emb_lds + (tid - HALF) * 10));

        LDS_BARRIER();                       // phase-2 rows visible

        int h2 = count - HALF;
        if (h2 > 0)
            writeback_half(sh_lds, emb_lds, out_sh, out_emb,
                           (size_t)(base + HALF), h2, tid);

        LDS_BARRIER();                       // staging reads done

        if (!have1) break;
        c = c1; c1 = c2;
        s0 = s1; d0 = d1; bx0 = bx1; by0 = by1; bz0 = bz1;
        s1 = s2; d1 = d2;
    }
}

extern "C" void kernel_launch(void* const* d_in, const int* in_sizes, int n_in,
                              void* d_out, int out_size, void* d_ws, size_t ws_size,
                              hipStream_t stream) {
    const float* pos  = (const float*)d_in[0];
    const float* qpos = (const float*)d_in[1];
    const int* esrc = (const int*)d_in[2];
    const int* edst = (const int*)d_in[3];
    int npos = in_sizes[0] / 3;   // 100000
    int n    = in_sizes[2];       // 4,000,000 edges

    float* out_sh  = (float*)d_out;
    float* out_emb = out_sh + (size_t)n * 9;

    size_t need = (size_t)npos * sizeof(float4);
    if (ws_size >= need) {
        float4* pos4 = (float4*)d_ws;
        int pgrid = (npos + 255) / 256;
        pad_kernel<<<pgrid, 256, 0, stream>>>(pos, pos4, npos);
        qsh_kernel<true><<<QSH_GRID, TPB, 0, stream>>>(
            pos, qpos, (const floatx4*)pos4, esrc, edst, out_sh, out_emb, n);
    } else {
        qsh_kernel<false><<<QSH_GRID, TPB, 0, stream>>>(
            pos, qpos, nullptr, esrc, edst, out_sh, out_emb, n);
    }
}

// Round 8
// 333.559 us; speedup vs baseline: 1.2254x; 1.0514x over previous
//
#include <hip/hip_runtime.h>

// QuerySHLayerDeprecated: per-edge SH(lmax=2) + smooth radial basis embed.
//   d_in[0] = pos        f32[100000*3]
//   d_in[1] = query_pos  f32[10000*3]
//   d_in[2] = edge_src   int32[4000000]  (rows of query_pos)
//   d_in[3] = edge_dst   int32[4000000]  (rows of pos)
// Output: edge_sh[4M*9] then edge_embed[4M*10], f32 flat concat.
//
// R11: R10 (qpos-in-LDS, 16 waves, persistent) = 350.7, new best, but
// miss-savings Y~70us partly eaten by structure cost X~60us. Ledger fit:
// gather bursts are issued mid-iteration and consumed at next iteration's
// start -> retire window ~0.5 iter < 15.4Kcy needed for 1024 misses ->
// miss pipe idles ~33% between bursts. Fix: depth-2 gather pipeline
// (gathers for c+1 AND c+2 in flight, idx 3 ahead, burst issued at TOP of
// loop before compute), and drop sched_barrier(0) (memory-clobbered
// lgkmcnt asm + s_barrier already order LDS ops; the pin only hurts).

#define SQRT3F 1.7320508075688772f
// SMOOTH_C * sqrt(10) = 1.14136 * e^2 * sqrt(10)
#define EMB_K 26.6692997f
#define TPB 1024
#define EPB 1024                 // edges per chunk (1 per thread)
#define HALF 512                 // staging rows per phase
#define NQF 30000                // qpos floats (10000*3) = 120000 B
#define QSH_GRID 256             // persistent: 1 block per CU

typedef float floatx4 __attribute__((ext_vector_type(4)));

__global__ __launch_bounds__(256) void pad_kernel(
    const float* __restrict__ pos, float4* __restrict__ pos4, int npos)
{
    int i = blockIdx.x * blockDim.x + threadIdx.x;
    if (i < npos)
        pos4[i] = make_float4(pos[3 * i + 0], pos[3 * i + 1], pos[3 * i + 2], 0.f);
}

// 9 SH values -> sh row (word stride 9: odd -> free 2-way bank alias),
// 10 embed values -> em2 (5 float2 zeros + <=2 scalar window overwrites;
// LDS pointer so the runtime index j never touches a register array).
__device__ __forceinline__ void compute_edge(
    float ax, float ay, float az, float bx, float by, float bz,
    float* __restrict__ sh, float2* __restrict__ em2)
{
    float vx = ax - bx, vy = ay - by, vz = az - bz;
    float r2 = vx * vx + vy * vy + vz * vz;
    float r = sqrtf(r2);
    float inv = (r > 0.f) ? (1.f / r) : 1.f;
    float x = vx * inv, y = vy * inv, z = vz * inv;

    sh[0] = 1.f;
    sh[1] = x;
    sh[2] = y;
    sh[3] = z;
    sh[4] = SQRT3F * x * z;
    sh[5] = SQRT3F * x * y;
    sh[6] = y * y - 0.5f * (x * x + z * z);
    sh[7] = SQRT3F * y * z;
    sh[8] = 0.5f * SQRT3F * (z * z - x * x);

#pragma unroll
    for (int j = 0; j < 5; ++j) em2[j] = make_float2(0.f, 0.f);

    // embed: t = 11*r; basis j nonzero only for t in (j, j+2); at most two
    // nonzero, j in {floor(t)-1, floor(t)}.
    float t = r * 11.f;
    int k = (int)t;
    float* e = (float*)em2;
#pragma unroll
    for (int m = 0; m < 2; ++m) {
        int j = k - 1 + m;
        float a = t - (float)j;
        float b = (float)(j + 2) - t;
        if (j >= 0 && j < 10 && a > 0.f && b > 0.f)
            e[j] = EMB_K * __expf(-(__frcp_rn(a) + __frcp_rn(b)));
    }
}

__device__ __forceinline__ void writeback_half(
    const float* __restrict__ sh_lds, const float* __restrict__ emb_lds,
    float* __restrict__ out_sh, float* __restrict__ out_emb,
    size_t obase, int h, int tid)
{
    if (h == HALF) {
        // 512*9 = 1152 float4s, 512*10 = 1280 float4s; 1024 threads.
        floatx4* osh4 = (floatx4*)(out_sh + obase * 9);
        floatx4* oem4 = (floatx4*)(out_emb + obase * 10);
        const floatx4* shv = (const floatx4*)sh_lds;
        const floatx4* emv = (const floatx4*)emb_lds;
        __builtin_nontemporal_store(shv[tid], osh4 + tid);
        if (tid + TPB < 1152)
            __builtin_nontemporal_store(shv[tid + TPB], osh4 + tid + TPB);
        __builtin_nontemporal_store(emv[tid], oem4 + tid);
        if (tid + TPB < 1280)
            __builtin_nontemporal_store(emv[tid + TPB], oem4 + tid + TPB);
    } else {
        float* osh = out_sh + obase * 9;
        float* oem = out_emb + obase * 10;
        int nsh = h * 9;
        for (int idx = tid; idx < nsh; idx += TPB)
            __builtin_nontemporal_store(sh_lds[idx], osh + idx);
        int nem = h * 10;
        for (int idx = tid; idx < nem; idx += TPB)
            __builtin_nontemporal_store(emb_lds[idx], oem + idx);
    }
}

// lgkmcnt-only barrier: orders LDS ops across waves WITHOUT draining
// vmcnt -> prefetch gathers stay in flight across phases. "memory"
// clobber forbids the compiler moving memory ops across it.
#define LDS_BARRIER() do {                                   \
    asm volatile("s_waitcnt lgkmcnt(0)" ::: "memory");       \
    __builtin_amdgcn_s_barrier();                            \
} while (0)

template <bool PAD>
__global__ __launch_bounds__(1024, 1) void qsh_kernel(
    const float* __restrict__ pos,
    const float* __restrict__ qpos,
    const floatx4* __restrict__ pos4,
    const int* __restrict__ esrc,
    const int* __restrict__ edst,
    float* __restrict__ out_sh,
    float* __restrict__ out_emb,
    int n)
{
    __shared__ float qp[NQF];                         // 120000 B
    __shared__ __align__(16) float sh_lds[HALF * 9];  // 18432 B
    __shared__ __align__(16) float emb_lds[HALF * 10];// 20480 B => 158912 B

    const int tid = threadIdx.x;

    // Stage the whole qpos table once per persistent block (coalesced x4;
    // 30000 floats = 7500 float4s exactly).
    {
        const floatx4* src = (const floatx4*)qpos;
        floatx4* dst = (floatx4*)qp;
        for (int i = tid; i < NQF / 4; i += TPB) dst[i] = src[i];
    }
    __syncthreads();

    const int nchunk = (n + EPB - 1) / EPB;
    const int G = gridDim.x;
    int c = blockIdx.x;
    if (c >= nchunk) return;

    // Depth-2 pipeline state:
    //   chunk c   : gather in regs (bx0)      [consumed this iter]
    //   chunk c+G : gather in flight (bx1)
    //   chunk c+2G: idx in regs (s2,d2); gather issued at loop top (bx2)
    //   chunk c+3G: idx issued at loop top
    int e0 = c * EPB + tid; if (e0 >= n) e0 = n - 1;
    int s0 = __builtin_nontemporal_load(esrc + e0);
    int d0 = __builtin_nontemporal_load(edst + e0);
    float bx0, by0, bz0;
    if (PAD) { floatx4 t = pos4[d0]; bx0 = t.x; by0 = t.y; bz0 = t.z; }
    else { bx0 = pos[3*d0]; by0 = pos[3*d0+1]; bz0 = pos[3*d0+2]; }

    int c1 = c + G;
    int s1 = s0, d1 = d0;
    float bx1 = bx0, by1 = by0, bz1 = bz0;
    if (c1 < nchunk) {
        int e1 = c1 * EPB + tid; if (e1 >= n) e1 = n - 1;
        s1 = __builtin_nontemporal_load(esrc + e1);
        d1 = __builtin_nontemporal_load(edst + e1);
        if (PAD) { floatx4 t = pos4[d1]; bx1 = t.x; by1 = t.y; bz1 = t.z; }
        else { bx1 = pos[3*d1]; by1 = pos[3*d1+1]; bz1 = pos[3*d1+2]; }
    }

    int c2 = c1 + G;
    int s2 = s1, d2 = d1;
    if (c2 < nchunk) {
        int e2 = c2 * EPB + tid; if (e2 >= n) e2 = n - 1;
        s2 = __builtin_nontemporal_load(esrc + e2);
        d2 = __builtin_nontemporal_load(edst + e2);
    }

    while (true) {
        const int base = c * EPB;
        const int count = min(EPB, n - base);
        const bool have1 = (c1 < nchunk);
        const bool have2 = (c2 < nchunk);

        // ---- TOP OF LOOP: feed the miss pipe first. Gather chunk c2,
        // idx chunk c3. These stay in flight across all 4 barriers below
        // (lgkmcnt-only) and for ~1.5 iterations before consumption.
        float bx2 = bx1, by2 = by1, bz2 = bz1;
        if (have2) {
            if (PAD) { floatx4 t = pos4[d2]; bx2 = t.x; by2 = t.y; bz2 = t.z; }
            else { bx2 = pos[3*d2]; by2 = pos[3*d2+1]; bz2 = pos[3*d2+2]; }
        }
        int c3 = c2 + G, s3 = s2, d3 = d2;
        if (have2 && c3 < nchunk) {
            int e3 = c3 * EPB + tid; if (e3 >= n) e3 = n - 1;
            s3 = __builtin_nontemporal_load(esrc + e3);
            d3 = __builtin_nontemporal_load(edst + e3);
        }

        // qpos for this thread's edge from LDS.
        float ax = qp[3 * s0], ay = qp[3 * s0 + 1], az = qp[3 * s0 + 2];

        // ---- phase 1 compute: edges [base, base+HALF) -> rows [0,HALF)
        // (waves 0-7 wait vmcnt for their bx0 only; newer loads unaffected)
        if (tid < HALF && tid < count)
            compute_edge(ax, ay, az, bx0, by0, bz0,
                         sh_lds + tid * 9, (float2*)(emb_lds + tid * 10));

        LDS_BARRIER();                       // phase-1 rows visible

        int h1 = min(HALF, count);
        writeback_half(sh_lds, emb_lds, out_sh, out_emb, (size_t)base, h1, tid);

        LDS_BARRIER();                       // staging reads done

        // ---- phase 2 compute: edges [base+HALF, base+count) -> rows [0,..)
        if (tid >= HALF && tid < count)
            compute_edge(ax, ay, az, bx0, by0, bz0,
                         sh_lds + (tid - HALF) * 9,
                         (float2*)(emb_lds + (tid - HALF) * 10));

        LDS_BARRIER();                       // phase-2 rows visible

        int h2 = count - HALF;
        if (h2 > 0)
            writeback_half(sh_lds, emb_lds, out_sh, out_emb,
                           (size_t)(base + HALF), h2, tid);

        LDS_BARRIER();                       // staging reads done

        if (!have1) break;
        c = c1; c1 = c2; c2 = c3;
        s0 = s1; d0 = d1; bx0 = bx1; by0 = by1; bz0 = bz1;
        s1 = s2; d1 = d2; bx1 = bx2; by1 = by2; bz1 = bz2;
        s2 = s3; d2 = d3;
    }
}

extern "C" void kernel_launch(void* const* d_in, const int* in_sizes, int n_in,
                              void* d_out, int out_size, void* d_ws, size_t ws_size,
                              hipStream_t stream) {
    const float* pos  = (const float*)d_in[0];
    const float* qpos = (const float*)d_in[1];
    const int* esrc = (const int*)d_in[2];
    const int* edst = (const int*)d_in[3];
    int npos = in_sizes[0] / 3;   // 100000
    int n    = in_sizes[2];       // 4,000,000 edges

    float* out_sh  = (float*)d_out;
    float* out_emb = out_sh + (size_t)n * 9;

    size_t need = (size_t)npos * sizeof(float4);
    if (ws_size >= need) {
        float4* pos4 = (float4*)d_ws;
        int pgrid = (npos + 255) / 256;
        pad_kernel<<<pgrid, 256, 0, stream>>>(pos, pos4, npos);
        qsh_kernel<true><<<QSH_GRID, TPB, 0, stream>>>(
            pos, qpos, (const floatx4*)pos4, esrc, edst, out_sh, out_emb, n);
    } else {
        qsh_kernel<false><<<QSH_GRID, TPB, 0, stream>>>(
            pos, qpos, nullptr, esrc, edst, out_sh, out_emb, n);
    }
}